// Round 4
// baseline (297.878 us; speedup 1.0000x reference)
//
#include <hip/hip_runtime.h>

// EnhancedHamiltonianEvolution: out = Hamilton(ql_n, Hamilton(g*x, conj(qr_n)))
// FFT removed: spectral_gate is constant along the transform (time) axis,
// so ifft(fft(x)*g).real == g*x exactly by DFT linearity.
// R1..R3: nontemporal load/store for the streaming x/out tensors (read-once/
// write-once — bypass cache allocation); 2 feature-groups per thread.
// clang ext_vector_type for nt builtins; quat_one returns by value (vector
// elements can't bind to float&).

constexpr int D_MODEL = 2048;
constexpr int QD      = 512;       // QUAT_DIM
constexpr int NF8     = QD / 8;    // 64 float4-pairs per component row

typedef float f32x4 __attribute__((ext_vector_type(4)));

struct Quat { float w, x, y, z; };

__device__ __forceinline__ Quat quat_one(
    float xw, float xx, float xy, float xz,      // input quaternion (one feature)
    float lw, float lx, float ly, float lz,      // raw q_left
    float rw, float rx, float ry, float rz,      // raw q_right
    float g)
{
    const float eps = 1e-8f;
    float linv = rsqrtf(lw*lw + lx*lx + ly*ly + lz*lz + eps);
    lw *= linv; lx *= linv; ly *= linv; lz *= linv;
    float rinv = rsqrtf(rw*rw + rx*rx + ry*ry + rz*rz + eps);
    // normalized conjugate of q_right
    float cw =  rw * rinv;
    float cx = -rx * rinv;
    float cy = -ry * rinv;
    float cz = -rz * rinv;
    // gate (exact replacement of fft->gate->ifft since gate is freq-constant)
    float aw = xw * g, ax = xx * g, ay = xy * g, az = xz * g;
    // t = H(a, c)   [x_filt * qr_conj]
    float tw = aw*cw - ax*cx - ay*cy - az*cz;
    float tx = aw*cx + ax*cw + ay*cz - az*cy;
    float ty = aw*cy - ax*cz + ay*cw + az*cx;
    float tz = aw*cz + ax*cy - ay*cx + az*cw;
    // o = H(l, t)   [ql * t]
    Quat o;
    o.w = lw*tw - lx*tx - ly*ty - lz*tz;
    o.x = lw*tx + lx*tw + ly*tz - lz*ty;
    o.y = lw*ty - lx*tz + ly*tw + lz*tx;
    o.z = lw*tz + lx*ty - ly*tx + lz*tw;
    return o;
}

__device__ __forceinline__ f32x4 nt_load4(const float* p) {
    return __builtin_nontemporal_load((const f32x4*)p);
}
__device__ __forceinline__ void nt_store4(float* p, f32x4 v) {
    __builtin_nontemporal_store(v, (f32x4*)p);
}

// process one float4 feature-group at (bt, f)
__device__ __forceinline__ void do_group(
    const float* __restrict__ x, float* __restrict__ out,
    const float* __restrict__ q_left, const float* __restrict__ q_right,
    const float* __restrict__ gate, int bt, int f)
{
    const f32x4 lw4 = *(const f32x4*)(q_left  + 0 * QD + f);
    const f32x4 lx4 = *(const f32x4*)(q_left  + 1 * QD + f);
    const f32x4 ly4 = *(const f32x4*)(q_left  + 2 * QD + f);
    const f32x4 lz4 = *(const f32x4*)(q_left  + 3 * QD + f);
    const f32x4 rw4 = *(const f32x4*)(q_right + 0 * QD + f);
    const f32x4 rx4 = *(const f32x4*)(q_right + 1 * QD + f);
    const f32x4 ry4 = *(const f32x4*)(q_right + 2 * QD + f);
    const f32x4 rz4 = *(const f32x4*)(q_right + 3 * QD + f);
    const f32x4 g4  = *(const f32x4*)(gate + f);

    size_t base = (size_t)bt * D_MODEL + f;
    const f32x4 xw4 = nt_load4(x + base + 0 * QD);
    const f32x4 xx4 = nt_load4(x + base + 1 * QD);
    const f32x4 xy4 = nt_load4(x + base + 2 * QD);
    const f32x4 xz4 = nt_load4(x + base + 3 * QD);

    Quat o0 = quat_one(xw4.x, xx4.x, xy4.x, xz4.x, lw4.x, lx4.x, ly4.x, lz4.x,
                       rw4.x, rx4.x, ry4.x, rz4.x, g4.x);
    Quat o1 = quat_one(xw4.y, xx4.y, xy4.y, xz4.y, lw4.y, lx4.y, ly4.y, lz4.y,
                       rw4.y, rx4.y, ry4.y, rz4.y, g4.y);
    Quat o2 = quat_one(xw4.z, xx4.z, xy4.z, xz4.z, lw4.z, lx4.z, ly4.z, lz4.z,
                       rw4.z, rx4.z, ry4.z, rz4.z, g4.z);
    Quat o3 = quat_one(xw4.w, xx4.w, xy4.w, xz4.w, lw4.w, lx4.w, ly4.w, lz4.w,
                       rw4.w, rx4.w, ry4.w, rz4.w, g4.w);

    f32x4 ow4 = { o0.w, o1.w, o2.w, o3.w };
    f32x4 ox4 = { o0.x, o1.x, o2.x, o3.x };
    f32x4 oy4 = { o0.y, o1.y, o2.y, o3.y };
    f32x4 oz4 = { o0.z, o1.z, o2.z, o3.z };

    nt_store4(out + base + 0 * QD, ow4);
    nt_store4(out + base + 1 * QD, ox4);
    nt_store4(out + base + 2 * QD, oy4);
    nt_store4(out + base + 3 * QD, oz4);
}

__global__ __launch_bounds__(256) void quat_rot_kernel(
    const float* __restrict__ x,
    const float* __restrict__ q_left,
    const float* __restrict__ q_right,
    const float* __restrict__ gate,
    float* __restrict__ out,
    int n_bt)
{
    int idx = blockIdx.x * blockDim.x + threadIdx.x;
    // each thread: 2 adjacent float4 groups (128 B of x, 128 B of out)
    int f8  = idx & (NF8 - 1);        // 0..63
    int bt  = idx >> 6;               // / NF8
    if (bt >= n_bt) return;
    int f = f8 << 3;                  // feature offset, 8 features per thread

    do_group(x, out, q_left, q_right, gate, bt, f);
    do_group(x, out, q_left, q_right, gate, bt, f + 4);
}

extern "C" void kernel_launch(void* const* d_in, const int* in_sizes, int n_in,
                              void* d_out, int out_size, void* d_ws, size_t ws_size,
                              hipStream_t stream) {
    const float* x      = (const float*)d_in[0];
    const float* q_left = (const float*)d_in[1];
    const float* q_right= (const float*)d_in[2];
    const float* gate   = (const float*)d_in[3];
    float* out          = (float*)d_out;

    int n_bt = in_sizes[0] / D_MODEL;          // B*T = 16384
    long total = (long)n_bt * NF8;             // threads (8 features each)
    int block = 256;
    int grid = (int)((total + block - 1) / block);
    quat_rot_kernel<<<grid, block, 0, stream>>>(x, q_left, q_right, gate, out, n_bt);
}